// Round 8
// baseline (276.847 us; speedup 1.0000x reference)
//
#include <hip/hip_runtime.h>
#include <hip/hip_bf16.h>

// SSIM loss, round 8: MFMA blur (r7 algebra, verified absmax=0) restructured
// for latency hiding: 8192 waves x 64-row strips, 48-slot LDS ring (14.3 KB
// /block), loads double-buffered one full iteration ahead of their hproc.
// hblur: D[16 rows][16 cols] = A(raw) x B(const band W[k-n-3])
// vblur: D[16 cols][16 rows] = A(transposed h ring) x same B

typedef float  f32x4   __attribute__((ext_vector_type(4)));
typedef short  short8  __attribute__((ext_vector_type(8)));
typedef short  short4v __attribute__((ext_vector_type(4)));
typedef float  float4v __attribute__((ext_vector_type(4)));

#define NBLOCK 4096     // x2 waves = 8192 waves
#define RSTR   56       // ring row stride (shorts): 112 B, 16B-mult, ~2-way banks

__device__ __forceinline__ short bf16s(float x) {
    __hip_bfloat16 h = __float2bfloat16(x);
    return __builtin_bit_cast(short, h);
}
__device__ __forceinline__ float bf16f(float x) {
    unsigned u = (unsigned)__builtin_bit_cast(unsigned short,
                                              __float2bfloat16(x)) << 16;
    return __builtin_bit_cast(float, u);
}

__global__ __launch_bounds__(128, 4)
void ssim_main(const float* __restrict__ pred, const float* __restrict__ targ,
               float* __restrict__ slotSum, unsigned int* __restrict__ grpCnt,
               unsigned int* __restrict__ finalCnt, float* __restrict__ out) {
    const float W[11] = {
        0.00102840f, 0.00759876f, 0.03600077f, 0.10936070f, 0.21300554f,
        0.26601173f,
        0.21300554f, 0.10936070f, 0.03600077f, 0.00759876f, 0.00102840f};

    __shared__ __align__(16) short hring[2][4][16][RSTR];   // 14,336 B
    __shared__ float wsum[2];

    const int w      = threadIdx.x >> 6;
    const int L      = threadIdx.x & 63;
    const int n      = L & 15;
    const int quad   = L >> 4;
    const int waveId = blockIdx.x * 2 + w;
    const int img    = waveId >> 8;         // 256 waves per image
    const int rem    = waveId & 255;
    const int q      = rem >> 5;            // 64-row quarter, 0..7
    const int stripe = rem & 31;
    const int c0     = stripe << 4;
    const int s0     = q << 2;              // 4 out tiles per wave
    const bool edge  = (stripe == 0) | (stripe == 31);

    const float* __restrict__ pim = pred + (size_t)img * 262144;
    const float* __restrict__ tim = targ + (size_t)img * 262144;

    float S = 0.f;
#pragma unroll
    for (int kk = 0; kk < 11; ++kk) S += bf16f(W[kk]);
    const float c2 = 1.0f / (S * S);

    short8 bw;
#pragma unroll
    for (int j = 0; j < 8; ++j) {
        const int d = quad * 8 + j - n - 3;
        bw[j] = bf16s((d >= 0 && d <= 10) ? W[d] : 0.f);
    }
    const f32x4 zc = {0.f, 0.f, 0.f, 0.f};

    float PA[8], TA[8], PB[8], TB[8];     // double-buffered raw tiles

    auto hload = [&](float (&P)[8], float (&T)[8], int Tt) {
        if ((unsigned)Tt > 31u) {
#pragma unroll
            for (int j = 0; j < 8; ++j) { P[j] = 0.f; T[j] = 0.f; }
            return;
        }
        const int r  = (Tt << 4) + n;
        const int cb = c0 - 8 + quad * 8;
        if (!edge) {
            const float4v* pp = (const float4v*)(pim + r * 512 + cb);
            const float4v* tp = (const float4v*)(tim + r * 512 + cb);
            const float4v p0 = pp[0], p1 = pp[1];
            const float4v t0 = tp[0], t1 = tp[1];
#pragma unroll
            for (int j = 0; j < 4; ++j) {
                P[j] = p0[j]; P[j + 4] = p1[j];
                T[j] = t0[j]; T[j + 4] = t1[j];
            }
        } else {
#pragma unroll
            for (int j = 0; j < 8; ++j) {
                const int col = cb + j;
                const int cc = min(max(col, 0), 511);
                const float pv = pim[r * 512 + cc];
                const float tv = tim[r * 512 + cc];
                const bool ok = (unsigned)col < 512u;
                P[j] = ok ? pv : 0.f;
                T[j] = ok ? tv : 0.f;
            }
        }
    };

    auto hproc = [&](float (&P)[8], float (&T)[8], int Tt) {
        const int Tm3   = (int)((unsigned)(Tt + 3) % 3u);   // row (Tt*16) mod 48
        const int wslot = Tm3 * 16 + quad * 4;
        short4v o[4];
        if ((unsigned)Tt > 31u) {
#pragma unroll
            for (int f = 0; f < 4; ++f) o[f] = (short4v){0, 0, 0, 0};
        } else {
            short8 fa[4];
#pragma unroll
            for (int j = 0; j < 8; ++j) {
                const float u = P[j] + T[j], v = P[j] - T[j];
                fa[0][j] = bf16s(P[j]);
                fa[1][j] = bf16s(T[j]);
                fa[2][j] = bf16s(u * u);
                fa[3][j] = bf16s(v * v);
            }
#pragma unroll
            for (int f = 0; f < 4; ++f) {
                const f32x4 d = __builtin_amdgcn_mfma_f32_16x16x32_bf16(
                    fa[f], bw, zc, 0, 0, 0);
                short4v ov;
#pragma unroll
                for (int r2 = 0; r2 < 4; ++r2) ov[r2] = bf16s(d[r2]);
                o[f] = ov;
            }
        }
#pragma unroll
        for (int f = 0; f < 4; ++f)
            *(short4v*)&hring[w][f][n][wslot] = o[f];      // ds_write_b64
    };

    // ---- prologue: tiles s0-1..s0+1 proc'd, s0+2 loaded-in-flight ----
    hload(PA, TA, s0 - 1);
    hload(PB, TB, s0);
    hproc(PA, TA, s0 - 1);
    hload(PA, TA, s0 + 1);
    hproc(PB, TB, s0);
    hload(PB, TB, s0 + 2);
    hproc(PA, TA, s0 + 1);

    float lsum = 0.f;
#pragma unroll
    for (int o = 0; o < 4; ++o) {
        const int s = s0 + o;
        // fire next-next tile's loads a full iteration ahead
        if (o == 0) hload(PA, TA, s0 + 3);
        if (o == 1) hload(PB, TB, s0 + 4);

        // vblur + ssim for out-tile s (ring rows s*16-8 .. s*16+23, mod 48)
        const int rs = (int)((unsigned)(s * 16 + 40) % 48u);
        int chunk = rs + quad * 8;
        if (chunk >= 48) chunk -= 48;
        f32x4 dv[4];
#pragma unroll
        for (int f = 0; f < 4; ++f) {
            const short8 af = *(const short8*)&hring[w][f][n][chunk]; // b128
            dv[f] = __builtin_amdgcn_mfma_f32_16x16x32_bf16(af, bw, zc, 0, 0, 0);
        }
#pragma unroll
        for (int r = 0; r < 4; ++r) {
            const float m1 = dv[0][r] * c2, m2 = dv[1][r] * c2;
            const float Av = dv[2][r] * c2, Bv = dv[3][r] * c2;
            const float m12  = m1 * m2;
            const float smsq = m1 * m1 + m2 * m2;
            const float s12  = __builtin_fmaf(0.25f, Av - Bv, -m12);
            const float s1s2 = __builtin_fmaf(0.5f,  Av + Bv, -smsq);
            const float num = __builtin_fmaf(2.f, m12, 1e-4f) *
                              __builtin_fmaf(2.f, s12, 9e-4f);
            const float den = (smsq + 1e-4f) * (s1s2 + 9e-4f);
            float rc = __builtin_amdgcn_rcpf(den);
            rc = rc * (2.f - den * rc);
            lsum = __builtin_fmaf(num, rc, lsum);
        }

        // process the tile whose loads were issued LAST iteration
        if (o == 0) hproc(PB, TB, s0 + 2);
        if (o == 1) hproc(PA, TA, s0 + 3);
        if (o == 2) hproc(PB, TB, s0 + 4);
    }

    // ---- hierarchical reduce: wave -> block -> 64 slots -> ticket ----
#pragma unroll
    for (int off = 32; off > 0; off >>= 1)
        lsum += __shfl_down(lsum, off, 64);
    if (L == 0) wsum[w] = lsum;
    __syncthreads();
    if (threadIdx.x == 0) {
        const float bs = wsum[0] + wsum[1];
        const int g = blockIdx.x & 63;            // 64 groups x 64 blocks
        atomicAdd(&slotSum[g * 16], bs);          // slots 64 B apart
        __threadfence();
        if (atomicAdd(&grpCnt[g * 16], 1u) == 63u) {
            __threadfence();
            if (atomicAdd(finalCnt, 1u) == 63u) {
                float sf = 0.f;
#pragma unroll
                for (int i = 0; i < 64; ++i)
                    sf += atomicAdd(&slotSum[i * 16], 0.f);
                out[0] = 1.0f - sf * (1.0f / 8388608.0f);
            }
        }
    }
}

extern "C" void kernel_launch(void* const* d_in, const int* in_sizes, int n_in,
                              void* d_out, int out_size, void* d_ws,
                              size_t ws_size, hipStream_t stream) {
    const float* pred = (const float*)d_in[0];
    const float* targ = (const float*)d_in[1];
    float* slotSum = (float*)d_ws;                              // 64 x 64 B
    unsigned int* grpCnt = (unsigned int*)((char*)d_ws + 4096); // 64 x 64 B
    unsigned int* finalCnt = (unsigned int*)((char*)d_ws + 8192);

    hipMemsetAsync(d_ws, 0, 8196, stream);
    ssim_main<<<dim3(NBLOCK), dim3(128), 0, stream>>>(pred, targ, slotSum,
                                                      grpCnt, finalCnt,
                                                      (float*)d_out);
    (void)in_sizes; (void)n_in; (void)out_size; (void)ws_size;
}

// Round 9
// 246.989 us; speedup vs baseline: 1.1209x; 1.1209x over previous
//
#include <hip/hip_runtime.h>
#include <hip/hip_bf16.h>

// SSIM loss, round 9: two streaming MFMA kernels, no intra-wave LDS ring.
// hpass: hblur via MFMA, D fragments stored directly to col-major bf16 ws
//        ws[f][img][col][row]  (D C-layout col=lane&15 -> out col, rows
//        quad*4+reg -> short4v store = natural col-major).
// vpass: lane loads short8 = 8 rows of its column from ws = the vblur MFMA
//        A-fragment directly (A[m=lane&15=col][k=quad*8+j=row]); 4 MFMA ->
//        ssim -> hierarchical atomic reduce (r7 scheme, verified).
// Band B-frag: B[k][n] = W[k-n-3] (verified absmax=0 in r6/r7).

typedef float  f32x4   __attribute__((ext_vector_type(4)));
typedef short  short8  __attribute__((ext_vector_type(8)));
typedef short  short4v __attribute__((ext_vector_type(4)));
typedef float  float4v __attribute__((ext_vector_type(4)));

#define NBLK 1024     // per pass: 8 col-panels x 4 row-chunks x 32 imgs
#define HOFF 16384    // ws byte offset of h area (reduction slots below)

__device__ __forceinline__ short bf16s(float x) {
    __hip_bfloat16 h = __float2bfloat16(x);
    return __builtin_bit_cast(short, h);
}
__device__ __forceinline__ float bf16f(float x) {
    unsigned u = (unsigned)__builtin_bit_cast(unsigned short,
                                              __float2bfloat16(x)) << 16;
    return __builtin_bit_cast(float, u);
}

#define W_INIT const float W[11] = { \
    0.00102840f, 0.00759876f, 0.03600077f, 0.10936070f, 0.21300554f, \
    0.26601173f, \
    0.21300554f, 0.10936070f, 0.03600077f, 0.00759876f, 0.00102840f}

__device__ __forceinline__ short8 band_frag(const float* W, int n, int q) {
    short8 bw;
#pragma unroll
    for (int j = 0; j < 8; ++j) {
        const int d = q * 8 + j - n - 3;
        bw[j] = bf16s((d >= 0 && d <= 10) ? W[d] : 0.f);
    }
    return bw;
}

// ---------------- pass 1: horizontal blur -> ws ----------------
__global__ __launch_bounds__(256, 4)
void hpass(const float* __restrict__ pred, const float* __restrict__ targ,
           short* __restrict__ hws) {
    W_INIT;
    const int w   = threadIdx.x >> 6;
    const int L   = threadIdx.x & 63;
    const int n   = L & 15;
    const int q   = L >> 4;
    const int b   = blockIdx.x;
    const int cp  = b & 7;             // col panel (64 cols)
    const int rc  = (b >> 3) & 3;      // row chunk (128 rows)
    const int img = b >> 5;
    const int c0  = cp * 64 + w * 16;  // wave's 16-col stripe
    const int T0  = rc * 8;            // 8 row-tiles of 16
    const bool edge = (c0 == 0) | (c0 == 496);

    const float* __restrict__ pim = pred + (size_t)img * 262144;
    const float* __restrict__ tim = targ + (size_t)img * 262144;
    const short8 bw = band_frag(W, n, q);
    const f32x4 zc = {0.f, 0.f, 0.f, 0.f};

    // ws addressing for this lane's stores: col c0+n, field stride 32 imgs
    short* __restrict__ wcol = hws + ((size_t)img * 512 + (c0 + n)) * 512;

    float PA[8], TA[8], PB[8], TB[8];

    auto hload = [&](float (&P)[8], float (&T)[8], int Tt) {
        const int r  = (Tt << 4) + n;
        const int cb = c0 - 8 + q * 8;
        if (!edge) {
            const float4v* pp = (const float4v*)(pim + r * 512 + cb);
            const float4v* tp = (const float4v*)(tim + r * 512 + cb);
            const float4v p0 = pp[0], p1 = pp[1];
            const float4v t0 = tp[0], t1 = tp[1];
#pragma unroll
            for (int j = 0; j < 4; ++j) {
                P[j] = p0[j]; P[j + 4] = p1[j];
                T[j] = t0[j]; T[j + 4] = t1[j];
            }
        } else {
#pragma unroll
            for (int j = 0; j < 8; ++j) {
                const int col = cb + j;
                const int cc = min(max(col, 0), 511);
                const float pv = pim[r * 512 + cc];
                const float tv = tim[r * 512 + cc];
                const bool ok = (unsigned)col < 512u;
                P[j] = ok ? pv : 0.f;
                T[j] = ok ? tv : 0.f;
            }
        }
    };

    auto hproc = [&](float (&P)[8], float (&T)[8], int Tt) {
        short8 fa[4];
#pragma unroll
        for (int j = 0; j < 8; ++j) {
            const float u = P[j] + T[j], v = P[j] - T[j];
            fa[0][j] = bf16s(P[j]);
            fa[1][j] = bf16s(T[j]);
            fa[2][j] = bf16s(u * u);
            fa[3][j] = bf16s(v * v);
        }
#pragma unroll
        for (int f = 0; f < 4; ++f) {
            const f32x4 d = __builtin_amdgcn_mfma_f32_16x16x32_bf16(
                fa[f], bw, zc, 0, 0, 0);
            short4v ov;
#pragma unroll
            for (int r2 = 0; r2 < 4; ++r2) ov[r2] = bf16s(d[r2]);
            // col-major store: rows Tt*16 + q*4 .. +4 of col c0+n, field f
            *(short4v*)(wcol + (size_t)f * 8388608 + (Tt << 4) + q * 4) = ov;
        }
    };

    hload(PA, TA, T0);
#pragma unroll
    for (int o = 0; o < 8; o += 2) {
        hload(PB, TB, T0 + o + 1);
        hproc(PA, TA, T0 + o);
        if (o < 6) hload(PA, TA, T0 + o + 2);
        hproc(PB, TB, T0 + o + 1);
    }
}

// ---------------- pass 2: vertical blur + ssim + reduce ----------------
__global__ __launch_bounds__(256, 4)
void vpass(const short* __restrict__ hws, float* __restrict__ slotSum,
           unsigned int* __restrict__ grpCnt,
           unsigned int* __restrict__ finalCnt, float* __restrict__ out) {
    W_INIT;
    __shared__ float wsum[4];

    const int w   = threadIdx.x >> 6;
    const int L   = threadIdx.x & 63;
    const int n   = L & 15;
    const int q   = L >> 4;
    const int b   = blockIdx.x;
    const int cp  = b & 7;
    const int rc  = (b >> 3) & 3;
    const int img = b >> 5;
    const int c0  = cp * 64 + w * 16;
    const int R0  = rc * 128;

    const short8 bw = band_frag(W, n, q);
    const f32x4 zc = {0.f, 0.f, 0.f, 0.f};

    float S = 0.f;
#pragma unroll
    for (int kk = 0; kk < 11; ++kk) S += bf16f(W[kk]);
    const float c2 = 1.0f / (S * S);

    // lane's column base (field stride added per load)
    const short* __restrict__ rcol = hws + ((size_t)img * 512 + (c0 + n)) * 512;

    short8 afA[4], afB[4];
    auto vload = [&](short8 (&af)[4], int R) {
        const int rowbase = R - 8 + q * 8;          // always chunk-aligned
        const bool ok = (unsigned)rowbase < 512u;   // OOB chunks are whole
#pragma unroll
        for (int f = 0; f < 4; ++f) {
            short8 v = {0, 0, 0, 0, 0, 0, 0, 0};
            if (ok) v = *(const short8*)(rcol + (size_t)f * 8388608 + rowbase);
            af[f] = v;
        }
    };

    float lsum = 0.f;
    vload(afA, R0);
#pragma unroll
    for (int s = 0; s < 8; ++s) {
        short8 (&cur)[4] = (s & 1) ? afB : afA;
        short8 (&nxt)[4] = (s & 1) ? afA : afB;
        if (s < 7) vload(nxt, R0 + (s + 1) * 16);

        f32x4 dv[4];
#pragma unroll
        for (int f = 0; f < 4; ++f)
            dv[f] = __builtin_amdgcn_mfma_f32_16x16x32_bf16(cur[f], bw, zc,
                                                            0, 0, 0);
#pragma unroll
        for (int r = 0; r < 4; ++r) {
            const float m1 = dv[0][r] * c2, m2 = dv[1][r] * c2;
            const float Av = dv[2][r] * c2, Bv = dv[3][r] * c2;
            const float m12  = m1 * m2;
            const float smsq = m1 * m1 + m2 * m2;
            const float s12  = __builtin_fmaf(0.25f, Av - Bv, -m12);
            const float s1s2 = __builtin_fmaf(0.5f,  Av + Bv, -smsq);
            const float num = __builtin_fmaf(2.f, m12, 1e-4f) *
                              __builtin_fmaf(2.f, s12, 9e-4f);
            const float den = (smsq + 1e-4f) * (s1s2 + 9e-4f);
            float rcp = __builtin_amdgcn_rcpf(den);
            rcp = rcp * (2.f - den * rcp);           // Newton step
            lsum = __builtin_fmaf(num, rcp, lsum);
        }
    }

    // hierarchical reduce: wave -> block -> 64 spread slots -> tickets
#pragma unroll
    for (int off = 32; off > 0; off >>= 1)
        lsum += __shfl_down(lsum, off, 64);
    if (L == 0) wsum[w] = lsum;
    __syncthreads();
    if (threadIdx.x == 0) {
        const float bs = wsum[0] + wsum[1] + wsum[2] + wsum[3];
        const int g = blockIdx.x & 63;               // 16 blocks per slot
        atomicAdd(&slotSum[g * 16], bs);
        __threadfence();
        if (atomicAdd(&grpCnt[g * 16], 1u) == 15u) {
            __threadfence();
            if (atomicAdd(finalCnt, 1u) == 63u) {
                float sf = 0.f;
#pragma unroll
                for (int i = 0; i < 64; ++i)
                    sf += atomicAdd(&slotSum[i * 16], 0.f);
                out[0] = 1.0f - sf * (1.0f / 8388608.0f);
            }
        }
    }
}

extern "C" void kernel_launch(void* const* d_in, const int* in_sizes, int n_in,
                              void* d_out, int out_size, void* d_ws,
                              size_t ws_size, hipStream_t stream) {
    const float* pred = (const float*)d_in[0];
    const float* targ = (const float*)d_in[1];
    float* slotSum = (float*)d_ws;                               // 64 x 64 B
    unsigned int* grpCnt = (unsigned int*)((char*)d_ws + 4096);  // 64 x 64 B
    unsigned int* finalCnt = (unsigned int*)((char*)d_ws + 8192);
    short* hws = (short*)((char*)d_ws + HOFF);   // 4 x 32 x 512 x 512 bf16

    hipMemsetAsync(d_ws, 0, 8196, stream);
    hpass<<<dim3(NBLK), dim3(256), 0, stream>>>(pred, targ, hws);
    vpass<<<dim3(NBLK), dim3(256), 0, stream>>>(hws, slotSum, grpCnt,
                                                finalCnt, (float*)d_out);
    (void)in_sizes; (void)n_in; (void)out_size; (void)ws_size;
}